// Round 3
// baseline (764.824 us; speedup 1.0000x reference)
//
#include <hip/hip_runtime.h>
#include <hip/hip_bf16.h>

// ---------------- constants ----------------
constexpr int B_    = 32;
constexpr int S_    = 512;
constexpr int INDIM = 256;
constexpr int KCTX  = 128;
constexpr int D_    = 128;
constexpr int H_    = 4;
constexpr int L_    = 2;
constexpr int HID_  = 512;
constexpr int TOTAL_ = 11 * D_ * D_ + 8 * D_;   // 181248
constexpr int OFF_AW  = 0;
constexpr int OFF_AB  = 3 * D_ * D_;            // 49152
constexpr int OFF_F1W = OFF_AB + 3 * D_;        // 49536
constexpr int OFF_F1B = OFF_F1W + 4 * D_ * D_;  // 115072
constexpr int OFF_F2W = OFF_F1B + 4 * D_;       // 115584
constexpr int OFF_F2B = OFF_F2W + 4 * D_ * D_;  // 181120

typedef __attribute__((ext_vector_type(8))) short short8;
typedef __attribute__((ext_vector_type(4))) short short4v;
typedef __attribute__((ext_vector_type(2))) short short2v;
typedef __attribute__((ext_vector_type(4))) float f32x4;

#define MFMA16 __builtin_amdgcn_mfma_f32_16x16x32_bf16

__device__ __forceinline__ short f2bf(float f) {
  __hip_bfloat16 h = __float2bfloat16(f);
  return __builtin_bit_cast(short, h);
}
__device__ __forceinline__ float bf2f(short s) {
  __hip_bfloat16 h = __builtin_bit_cast(__hip_bfloat16, s);
  return __bfloat162float(h);
}
// exact split: x = hi + lo + O(2^-18 |x|)
struct bfpair { short hi, lo; };
__device__ __forceinline__ bfpair split2p(float x) {
  bfpair p;
  p.hi = f2bf(x);
  p.lo = f2bf(x - bf2f(p.hi));
  return p;
}

// ---------------- fp32 -> (hi, lo) bf16 planes ----------------
__global__ void k_cvt2(const float* __restrict__ in, short* __restrict__ oh,
                       short* __restrict__ ol, int n) {
  int i = (blockIdx.x * blockDim.x + threadIdx.x) * 4;
  if (i < n) {
    float4 v = *(const float4*)(in + i);
    short4v h4, l4;
    bfpair p;
    p = split2p(v.x); h4[0] = p.hi; l4[0] = p.lo;
    p = split2p(v.y); h4[1] = p.hi; l4[1] = p.lo;
    p = split2p(v.z); h4[2] = p.hi; l4[2] = p.lo;
    p = split2p(v.w); h4[3] = p.hi; l4[3] = p.lo;
    *(short4v*)(oh + i) = h4;
    *(short4v*)(ol + i) = l4;
  }
}

// ---------------- hid = relu(ctx @ hfc1_w^T + b), split planes out ----------
__global__ __launch_bounds__(512) void k_hid(const float* __restrict__ cvec,
                                             const float* __restrict__ w,
                                             const float* __restrict__ bias,
                                             short* __restrict__ hh,
                                             short* __restrict__ hl) {
  int lb = blockIdx.x;            // l*32 + b
  int b  = lb & 31;
  int j  = threadIdx.x;
  __shared__ float cs[KCTX];
  if (j < KCTX) cs[j] = cvec[b * KCTX + j];
  __syncthreads();
  int l = lb >> 5;
  const float* wr = w + (long)(l * HID_ + j) * KCTX;
  float s = bias[l * HID_ + j];
  #pragma unroll
  for (int c = 0; c < KCTX; c += 4) {
    float4 cv = *(const float4*)(cs + c);
    float4 wv = *(const float4*)(wr + c);
    s += cv.x * wv.x + cv.y * wv.y + cv.z * wv.z + cv.w * wv.w;
  }
  s = fmaxf(s, 0.f);
  bfpair p = split2p(s);
  hh[(long)lb * HID_ + j] = p.hi;
  hl[(long)lb * HID_ + j] = p.lo;
}

// ---------------- flat = hid @ hfc2_w^T + b, split planes out ----------------
__global__ __launch_bounds__(256) void k_flat(const short* __restrict__ hidh,
                                              const short* __restrict__ hidl,
                                              const float* __restrict__ W,
                                              const float* __restrict__ bias,
                                              short* __restrict__ fh,
                                              short* __restrict__ fl) {
  const int tid  = threadIdx.x;
  const int wave = tid >> 6, lane = tid & 63;
  const int r    = lane & 15, ksub = (lane >> 4) * 8;
  const int trow = (blockIdx.x * 4 + wave) * 16 + r;
  const float* wp = W + (long)trow * HID_ + ksub;
  const short* hh0 = hidh + r * HID_ + ksub;
  const short* hh1 = hh0 + 16 * HID_;
  const short* hl0 = hidl + r * HID_ + ksub;
  const short* hl1 = hl0 + 16 * HID_;
  f32x4 acc0 = {0, 0, 0, 0}, acc1 = {0, 0, 0, 0};
  #pragma unroll 4
  for (int ks = 0; ks < 16; ++ks) {
    int k = ks * 32;
    short8 ah0 = *(const short8*)(hh0 + k);
    short8 ah1 = *(const short8*)(hh1 + k);
    short8 al0 = *(const short8*)(hl0 + k);
    short8 al1 = *(const short8*)(hl1 + k);
    float4 w0 = *(const float4*)(wp + k);
    float4 w1 = *(const float4*)(wp + k + 4);
    short8 wh, wl;
    bfpair p;
    p = split2p(w0.x); wh[0] = p.hi; wl[0] = p.lo;
    p = split2p(w0.y); wh[1] = p.hi; wl[1] = p.lo;
    p = split2p(w0.z); wh[2] = p.hi; wl[2] = p.lo;
    p = split2p(w0.w); wh[3] = p.hi; wl[3] = p.lo;
    p = split2p(w1.x); wh[4] = p.hi; wl[4] = p.lo;
    p = split2p(w1.y); wh[5] = p.hi; wl[5] = p.lo;
    p = split2p(w1.z); wh[6] = p.hi; wl[6] = p.lo;
    p = split2p(w1.w); wh[7] = p.hi; wl[7] = p.lo;
    acc0 = MFMA16(ah0, wl, acc0, 0, 0, 0);
    acc0 = MFMA16(al0, wh, acc0, 0, 0, 0);
    acc0 = MFMA16(ah0, wh, acc0, 0, 0, 0);
    acc1 = MFMA16(ah1, wl, acc1, 0, 0, 0);
    acc1 = MFMA16(al1, wh, acc1, 0, 0, 0);
    acc1 = MFMA16(ah1, wh, acc1, 0, 0, 0);
  }
  float bv = bias[trow];
  #pragma unroll
  for (int reg = 0; reg < 4; ++reg) {
    int brow = (lane >> 4) * 4 + reg;
    bfpair p0 = split2p(acc0[reg] + bv);
    fh[(long)brow * TOTAL_ + trow] = p0.hi;
    fl[(long)brow * TOTAL_ + trow] = p0.lo;
    bfpair p1 = split2p(acc1[reg] + bv);
    fh[(long)(brow + 16) * TOTAL_ + trow] = p1.hi;
    fl[(long)(brow + 16) * TOTAL_ + trow] = p1.lo;
  }
}

// ---------------- generic batched split-MFMA GEMM ----------------
// out[b][m][n] = act( sum_k A[b][m][k]*W[b][n][k] + bias[n] )
// EPI: 0 = split planes out (p0=Oh, p1=Ol, pitch N); 1 = in_proj (+pe,
//      p0=h_f f32, p1=h_hi, p2=h_lo, pitch 128); 2 = f32 out (p0, pitch N);
//      3 = vt transposed split (p0=vth, p1=vtl).
// BIAS: 0 = f32 vector biasF; 1 = split planes (bh,bl) at batch stride sB.
template <int K, int EPI, bool RELU, int BIAS>
__global__ __launch_bounds__(256) void k_gemm(const short* __restrict__ Ah,
                                              const short* __restrict__ Al, long sA,
                                              const short* __restrict__ Wh,
                                              const short* __restrict__ Wl, long sW,
                                              const short* __restrict__ bh,
                                              const short* __restrict__ bl, long sB,
                                              const float* __restrict__ biasF,
                                              void* __restrict__ p0,
                                              void* __restrict__ p1,
                                              void* __restrict__ p2,
                                              const float* __restrict__ pe,
                                              int N) {
  const int tid  = threadIdx.x;
  const int wave = tid >> 6, lane = tid & 63;
  const int r    = lane & 15, ksub = (lane >> 4) * 8;
  const int b    = blockIdx.z;
  const int m0   = blockIdx.y * 64 + (wave & 1) * 32;
  const int n0   = blockIdx.x * 64 + (wave >> 1) * 32;
  const short* pah0 = Ah + (long)b * sA + (long)(m0 + r) * K + ksub;
  const short* pah1 = pah0 + 16 * K;
  const short* pal0 = Al + (long)b * sA + (long)(m0 + r) * K + ksub;
  const short* pal1 = pal0 + 16 * K;
  const short* pwh0 = Wh + (long)b * sW + (long)(n0 + r) * K + ksub;
  const short* pwh1 = pwh0 + 16 * K;
  const short* pwl0 = Wl + (long)b * sW + (long)(n0 + r) * K + ksub;
  const short* pwl1 = pwl0 + 16 * K;
  f32x4 acc[2][2] = {{{0,0,0,0},{0,0,0,0}},{{0,0,0,0},{0,0,0,0}}};
  for (int k0 = 0; k0 < K; k0 += 32) {
    short8 ah0 = *(const short8*)(pah0 + k0);
    short8 ah1 = *(const short8*)(pah1 + k0);
    short8 al0 = *(const short8*)(pal0 + k0);
    short8 al1 = *(const short8*)(pal1 + k0);
    short8 wh0 = *(const short8*)(pwh0 + k0);
    short8 wh1 = *(const short8*)(pwh1 + k0);
    short8 wl0 = *(const short8*)(pwl0 + k0);
    short8 wl1 = *(const short8*)(pwl1 + k0);
    acc[0][0] = MFMA16(ah0, wl0, acc[0][0], 0, 0, 0);
    acc[0][0] = MFMA16(al0, wh0, acc[0][0], 0, 0, 0);
    acc[0][0] = MFMA16(ah0, wh0, acc[0][0], 0, 0, 0);
    acc[0][1] = MFMA16(ah0, wl1, acc[0][1], 0, 0, 0);
    acc[0][1] = MFMA16(al0, wh1, acc[0][1], 0, 0, 0);
    acc[0][1] = MFMA16(ah0, wh1, acc[0][1], 0, 0, 0);
    acc[1][0] = MFMA16(ah1, wl0, acc[1][0], 0, 0, 0);
    acc[1][0] = MFMA16(al1, wh0, acc[1][0], 0, 0, 0);
    acc[1][0] = MFMA16(ah1, wh0, acc[1][0], 0, 0, 0);
    acc[1][1] = MFMA16(ah1, wl1, acc[1][1], 0, 0, 0);
    acc[1][1] = MFMA16(al1, wh1, acc[1][1], 0, 0, 0);
    acc[1][1] = MFMA16(ah1, wh1, acc[1][1], 0, 0, 0);
  }
  #pragma unroll
  for (int ni = 0; ni < 2; ++ni) {
    int ccol = n0 + ni * 16 + r;
    float bv;
    if constexpr (BIAS == 0) bv = biasF[ccol];
    else bv = bf2f(bh[(long)b * sB + ccol]) + bf2f(bl[(long)b * sB + ccol]);
    #pragma unroll
    for (int mi = 0; mi < 2; ++mi) {
      #pragma unroll
      for (int reg = 0; reg < 4; ++reg) {
        int crow = m0 + mi * 16 + (lane >> 4) * 4 + reg;
        float v = acc[mi][ni][reg] + bv;
        if constexpr (RELU) v = fmaxf(v, 0.f);
        if constexpr (EPI == 0) {
          bfpair sp = split2p(v);
          ((short*)p0)[((long)b * S_ + crow) * (long)N + ccol] = sp.hi;
          ((short*)p1)[((long)b * S_ + crow) * (long)N + ccol] = sp.lo;
        } else if constexpr (EPI == 1) {
          v += pe[(long)crow * D_ + ccol];
          ((float*)p0)[((long)b * S_ + crow) * (long)D_ + ccol] = v;
          bfpair sp = split2p(v);
          ((short*)p1)[((long)b * S_ + crow) * (long)D_ + ccol] = sp.hi;
          ((short*)p2)[((long)b * S_ + crow) * (long)D_ + ccol] = sp.lo;
        } else if constexpr (EPI == 2) {
          ((float*)p0)[((long)b * S_ + crow) * (long)N + ccol] = v;
        } else {  // EPI == 3 : vt[b][h][d][s]
          int hd = ccol >> 5, dd = ccol & 31;
          long idx = ((long)(b * H_ + hd) * 32 + dd) * (long)S_ + crow;
          bfpair sp = split2p(v);
          ((short*)p0)[idx] = sp.hi;
          ((short*)p1)[idx] = sp.lo;
        }
      }
    }
  }
}

// ---------------- attention ----------------
__global__ __launch_bounds__(128) void k_attn(const short* __restrict__ qkh,
                                              const short* __restrict__ qkl,
                                              const short* __restrict__ vth,
                                              const short* __restrict__ vtl,
                                              short* __restrict__ ch,
                                              short* __restrict__ cl) {
  __shared__ __align__(16) float scr[2][16][516];
  const int tid  = threadIdx.x;
  const int wave = tid >> 6, lane = tid & 63;
  const int r    = lane & 15, ksub = (lane >> 4) * 8;
  const int b = blockIdx.z, hh = blockIdx.y;
  const int m0 = blockIdx.x * 32 + wave * 16;
  const long qoff = (long)b * S_ * 256 + hh * 32 + ksub;
  short8 qh = *(const short8*)(qkh + qoff + (long)(m0 + r) * 256);
  short8 ql = *(const short8*)(qkl + qoff + (long)(m0 + r) * 256);
  const float sc = 0.17677669529663687f;  // 1/sqrt(32)
  for (int n0 = 0; n0 < S_; n0 += 16) {
    short8 kh = *(const short8*)(qkh + qoff + 128 + (long)(n0 + r) * 256);
    short8 kl = *(const short8*)(qkl + qoff + 128 + (long)(n0 + r) * 256);
    f32x4 s = {0, 0, 0, 0};
    s = MFMA16(qh, kl, s, 0, 0, 0);
    s = MFMA16(ql, kh, s, 0, 0, 0);
    s = MFMA16(qh, kh, s, 0, 0, 0);
    #pragma unroll
    for (int reg = 0; reg < 4; ++reg)
      scr[wave][(lane >> 4) * 4 + reg][n0 + r] = s[reg] * sc;
  }
  __syncthreads();
  for (int row = 0; row < 16; ++row) {
    float v[8];
    #pragma unroll
    for (int i = 0; i < 8; ++i) v[i] = scr[wave][row][lane + i * 64];
    float m = v[0];
    #pragma unroll
    for (int i = 1; i < 8; ++i) m = fmaxf(m, v[i]);
    #pragma unroll
    for (int o = 32; o > 0; o >>= 1) m = fmaxf(m, __shfl_xor(m, o));
    float ssum = 0.f;
    #pragma unroll
    for (int i = 0; i < 8; ++i) { v[i] = __expf(v[i] - m); ssum += v[i]; }
    #pragma unroll
    for (int o = 32; o > 0; o >>= 1) ssum += __shfl_xor(ssum, o);
    float inv = 1.f / ssum;
    #pragma unroll
    for (int i = 0; i < 8; ++i) scr[wave][row][lane + i * 64] = v[i] * inv;
  }
  __syncthreads();
  f32x4 o0 = {0, 0, 0, 0}, o1 = {0, 0, 0, 0};
  const short* vhb = vth + (long)(b * H_ + hh) * 32 * S_;
  const short* vlb = vtl + (long)(b * H_ + hh) * 32 * S_;
  for (int kt = 0; kt < 16; ++kt) {
    float4 pv0 = *(const float4*)&scr[wave][r][kt * 32 + ksub];
    float4 pv1 = *(const float4*)&scr[wave][r][kt * 32 + ksub + 4];
    short8 pah, pal;
    bfpair p;
    p = split2p(pv0.x); pah[0] = p.hi; pal[0] = p.lo;
    p = split2p(pv0.y); pah[1] = p.hi; pal[1] = p.lo;
    p = split2p(pv0.z); pah[2] = p.hi; pal[2] = p.lo;
    p = split2p(pv0.w); pah[3] = p.hi; pal[3] = p.lo;
    p = split2p(pv1.x); pah[4] = p.hi; pal[4] = p.lo;
    p = split2p(pv1.y); pah[5] = p.hi; pal[5] = p.lo;
    p = split2p(pv1.z); pah[6] = p.hi; pal[6] = p.lo;
    p = split2p(pv1.w); pah[7] = p.hi; pal[7] = p.lo;
    short8 vh0 = *(const short8*)(vhb + (long)r * S_ + kt * 32 + ksub);
    short8 vh1 = *(const short8*)(vhb + (long)(16 + r) * S_ + kt * 32 + ksub);
    short8 vl0 = *(const short8*)(vlb + (long)r * S_ + kt * 32 + ksub);
    short8 vl1 = *(const short8*)(vlb + (long)(16 + r) * S_ + kt * 32 + ksub);
    o0 = MFMA16(pah, vl0, o0, 0, 0, 0);
    o0 = MFMA16(pal, vh0, o0, 0, 0, 0);
    o0 = MFMA16(pah, vh0, o0, 0, 0, 0);
    o1 = MFMA16(pah, vl1, o1, 0, 0, 0);
    o1 = MFMA16(pal, vh1, o1, 0, 0, 0);
    o1 = MFMA16(pah, vh1, o1, 0, 0, 0);
  }
  #pragma unroll
  for (int reg = 0; reg < 4; ++reg) {
    int srow = m0 + (lane >> 4) * 4 + reg;
    long base = ((long)b * S_ + srow) * D_ + hh * 32;
    bfpair sp0 = split2p(o0[reg]);
    ch[base + r] = sp0.hi; cl[base + r] = sp0.lo;
    bfpair sp1 = split2p(o1[reg]);
    ch[base + 16 + r] = sp1.hi; cl[base + 16 + r] = sp1.lo;
  }
}

// ---------------- layernorm: h = LN(h + alpha*y)*g + b ----------
__global__ __launch_bounds__(256) void k_ln(const float* hin, const float* __restrict__ y,
                                            const float* __restrict__ g,
                                            const float* __restrict__ bta,
                                            const float* __restrict__ alpha,
                                            float* hout, short* __restrict__ hh,
                                            short* __restrict__ hl) {
  long row = (long)blockIdx.x * 4 + (threadIdx.x >> 6);
  int lane = threadIdx.x & 63;
  float a = alpha[0];
  long base = row * D_;
  int c = lane * 2;
  float2 hv = *(const float2*)(hin + base + c);
  float2 yv = *(const float2*)(y + base + c);
  float t0 = hv.x + a * yv.x, t1 = hv.y + a * yv.y;
  float s = t0 + t1;
  #pragma unroll
  for (int o = 32; o > 0; o >>= 1) s += __shfl_xor(s, o);
  float mu = s * (1.f / 128.f);
  float d0 = t0 - mu, d1 = t1 - mu;
  float q = d0 * d0 + d1 * d1;
  #pragma unroll
  for (int o = 32; o > 0; o >>= 1) q += __shfl_xor(q, o);
  float inv = rsqrtf(q * (1.f / 128.f) + 1e-5f);
  float o0 = d0 * inv * g[c] + bta[c];
  float o1 = d1 * inv * g[c + 1] + bta[c + 1];
  float2 ov = {o0, o1};
  *(float2*)(hout + base + c) = ov;
  short2v hv2, lv2;
  bfpair p0 = split2p(o0);
  bfpair p1 = split2p(o1);
  hv2[0] = p0.hi; lv2[0] = p0.lo;
  hv2[1] = p1.hi; lv2[1] = p1.lo;
  *(short2v*)(hh + base + c) = hv2;
  *(short2v*)(hl + base + c) = lv2;
}

// ---------------- head ----------------
__global__ __launch_bounds__(64) void k_head(const float* __restrict__ h,
                                             const float* __restrict__ hw,
                                             const float* __restrict__ hb,
                                             float* __restrict__ out) {
  int b = blockIdx.x, lane = threadIdx.x;
  const float* hr = h + ((long)b * S_ + (S_ - 1)) * D_;
  float v = hr[lane] * hw[lane] + hr[lane + 64] * hw[lane + 64];
  #pragma unroll
  for (int o = 32; o > 0; o >>= 1) v += __shfl_xor(v, o);
  if (lane == 0) out[b] = v + hb[0];
}

// ---------------- host ----------------
extern "C" void kernel_launch(void* const* d_in, const int* in_sizes, int n_in,
                              void* d_out, int out_size, void* d_ws, size_t ws_size,
                              hipStream_t stream) {
  const float* x    = (const float*)d_in[0];
  const float* cvec = (const float*)d_in[1];
  const float* ipw  = (const float*)d_in[2];
  const float* ipb  = (const float*)d_in[3];
  const float* pe   = (const float*)d_in[4];
  const float* h1w  = (const float*)d_in[5];
  const float* h1b  = (const float*)d_in[6];
  const float* h2w  = (const float*)d_in[7];
  const float* h2b  = (const float*)d_in[8];
  const float* opw  = (const float*)d_in[9];
  const float* opb  = (const float*)d_in[10];
  const float* ln1g = (const float*)d_in[11];
  const float* ln1b = (const float*)d_in[12];
  const float* ln2g = (const float*)d_in[13];
  const float* ln2b = (const float*)d_in[14];
  const float* a1   = (const float*)d_in[15];
  const float* a2   = (const float*)d_in[16];
  const float* hw   = (const float*)d_in[17];
  const float* hb   = (const float*)d_in[18];
  float* out = (float*)d_out;

  char* ws = (char*)d_ws;
  size_t off = 0;
  auto alloc = [&](size_t n) { void* p = ws + off; off = (off + n + 255) & ~(size_t)255; return p; };

  short* ff1h  = (short*)alloc((size_t)B_ * S_ * 4 * D_ * 2);  // 16.8 MB, aliases x_hi
  short* ff1l  = (short*)alloc((size_t)B_ * S_ * 4 * D_ * 2);  // 16.8 MB, aliases x_lo
  short* x_hi  = ff1h;   // x planes dead before ff1 written
  short* x_lo  = ff1l;
  float* h_f   = (float*)alloc((size_t)B_ * S_ * D_ * 4);
  short* h_hi  = (short*)alloc((size_t)B_ * S_ * D_ * 2);
  short* h_lo  = (short*)alloc((size_t)B_ * S_ * D_ * 2);
  short* hidh  = (short*)alloc((size_t)L_ * B_ * HID_ * 2);
  short* hidl  = (short*)alloc((size_t)L_ * B_ * HID_ * 2);
  short* fh    = (short*)alloc((size_t)B_ * TOTAL_ * 2);
  short* fl    = (short*)alloc((size_t)B_ * TOTAL_ * 2);
  short* qkh   = (short*)alloc((size_t)B_ * S_ * 256 * 2);     // aliased as yb (same bytes)
  short* qkl   = (short*)alloc((size_t)B_ * S_ * 256 * 2);
  float* yb    = (float*)qkh;                                  // qk dead after k_attn
  short* vth   = (short*)alloc((size_t)B_ * H_ * 32 * S_ * 2);
  short* vtl   = (short*)alloc((size_t)B_ * H_ * 32 * S_ * 2);
  short* cxh   = (short*)alloc((size_t)B_ * S_ * D_ * 2);
  short* cxl   = (short*)alloc((size_t)B_ * S_ * D_ * 2);
  short* ipwh  = (short*)alloc((size_t)D_ * INDIM * 2);
  short* ipwl  = (short*)alloc((size_t)D_ * INDIM * 2);
  short* opwh  = (short*)alloc((size_t)L_ * D_ * D_ * 2);
  short* opwl  = (short*)alloc((size_t)L_ * D_ * D_ * 2);

  // conversions to split planes
  k_cvt2<<<(B_ * S_ * INDIM / 4 + 255) / 256, 256, 0, stream>>>(x, x_hi, x_lo, B_ * S_ * INDIM);
  k_cvt2<<<(D_ * INDIM / 4 + 255) / 256, 256, 0, stream>>>(ipw, ipwh, ipwl, D_ * INDIM);
  k_cvt2<<<(L_ * D_ * D_ / 4 + 255) / 256, 256, 0, stream>>>(opw, opwh, opwl, L_ * D_ * D_);

  k_hid<<<L_ * B_, 512, 0, stream>>>(cvec, h1w, h1b, hidh, hidl);

  // h = x @ in_proj^T + b + pe
  k_gemm<INDIM, 1, false, 0><<<dim3(2, 8, B_), 256, 0, stream>>>(
      x_hi, x_lo, (long)S_ * INDIM, ipwh, ipwl, 0, nullptr, nullptr, 0, ipb,
      h_f, h_hi, h_lo, pe, D_);

  for (int l = 0; l < L_; ++l) {
    k_flat<<<TOTAL_ / 64, 256, 0, stream>>>(hidh + (long)l * B_ * HID_,
                                            hidl + (long)l * B_ * HID_,
                                            h2w + (long)l * TOTAL_ * HID_,
                                            h2b + (long)l * TOTAL_, fh, fl);
    // q|k
    k_gemm<D_, 0, false, 1><<<dim3(4, 8, B_), 256, 0, stream>>>(
        h_hi, h_lo, (long)S_ * D_, fh + OFF_AW, fl + OFF_AW, (long)TOTAL_,
        fh + OFF_AB, fl + OFF_AB, (long)TOTAL_, nullptr, qkh, qkl, nullptr, nullptr, 256);
    // v -> transposed vt
    k_gemm<D_, 3, false, 1><<<dim3(2, 8, B_), 256, 0, stream>>>(
        h_hi, h_lo, (long)S_ * D_, fh + OFF_AW + 256 * D_, fl + OFF_AW + 256 * D_,
        (long)TOTAL_, fh + OFF_AB + 256, fl + OFF_AB + 256, (long)TOTAL_, nullptr,
        vth, vtl, nullptr, nullptr, 128);
    k_attn<<<dim3(S_ / 32, H_, B_), 128, 0, stream>>>(qkh, qkl, vth, vtl, cxh, cxl);
    // out_proj -> yb (f32)
    k_gemm<D_, 2, false, 0><<<dim3(2, 8, B_), 256, 0, stream>>>(
        cxh, cxl, (long)S_ * D_, opwh + (long)l * D_ * D_, opwl + (long)l * D_ * D_, 0,
        nullptr, nullptr, 0, opb + l * D_, yb, nullptr, nullptr, nullptr, D_);
    k_ln<<<B_ * S_ / 4, 256, 0, stream>>>(h_f, yb, ln1g + l * D_, ln1b + l * D_,
                                          a1 + l, h_f, h_hi, h_lo);
    // ffn1 (relu)
    k_gemm<D_, 0, true, 1><<<dim3(8, 8, B_), 256, 0, stream>>>(
        h_hi, h_lo, (long)S_ * D_, fh + OFF_F1W, fl + OFF_F1W, (long)TOTAL_,
        fh + OFF_F1B, fl + OFF_F1B, (long)TOTAL_, nullptr, ff1h, ff1l, nullptr, nullptr, 4 * D_);
    // ffn2 -> yb (f32)
    k_gemm<4 * D_, 2, false, 1><<<dim3(2, 8, B_), 256, 0, stream>>>(
        ff1h, ff1l, (long)S_ * 4 * D_, fh + OFF_F2W, fl + OFF_F2W, (long)TOTAL_,
        fh + OFF_F2B, fl + OFF_F2B, (long)TOTAL_, nullptr, yb, nullptr, nullptr, nullptr, D_);
    k_ln<<<B_ * S_ / 4, 256, 0, stream>>>(h_f, yb, ln2g + l * D_, ln2b + l * D_,
                                          a2 + l, h_f, h_hi, h_lo);
  }
  k_head<<<B_, 64, 0, stream>>>(h_f, hw, hb, out);
}

// Round 4
// 561.023 us; speedup vs baseline: 1.3633x; 1.3633x over previous
//
#include <hip/hip_runtime.h>
#include <hip/hip_bf16.h>

// ---------------- constants ----------------
constexpr int B_    = 32;
constexpr int S_    = 512;
constexpr int INDIM = 256;
constexpr int KCTX  = 128;
constexpr int D_    = 128;
constexpr int H_    = 4;
constexpr int L_    = 2;
constexpr int HID_  = 512;
constexpr int TOTAL_ = 11 * D_ * D_ + 8 * D_;   // 181248
constexpr int OFF_AB  = 3 * D_ * D_;            // 49152
constexpr int OFF_F1W = OFF_AB + 3 * D_;        // 49536
constexpr int OFF_F1B = OFF_F1W + 4 * D_ * D_;  // 115072
constexpr int OFF_F2W = OFF_F1B + 4 * D_;       // 115584
constexpr int OFF_F2B = OFF_F2W + 4 * D_ * D_;  // 181120

typedef __attribute__((ext_vector_type(8))) short short8;
typedef __attribute__((ext_vector_type(4))) short short4v;
typedef __attribute__((ext_vector_type(2))) short short2v;
typedef __attribute__((ext_vector_type(4))) float f32x4;

#define MFMA16 __builtin_amdgcn_mfma_f32_16x16x32_bf16

__device__ __forceinline__ short f2bf(float f) {
  __hip_bfloat16 h = __float2bfloat16(f);
  return __builtin_bit_cast(short, h);
}
__device__ __forceinline__ float bf2f(short s) {
  __hip_bfloat16 h = __builtin_bit_cast(__hip_bfloat16, s);
  return __bfloat162float(h);
}
struct bfpair { short hi, lo; };
__device__ __forceinline__ bfpair split2p(float x) {
  bfpair p;
  p.hi = f2bf(x);
  p.lo = f2bf(x - bf2f(p.hi));
  return p;
}

// Fragment-tiled (FT) layout: matrix (rows, K) stored as 16x8 tiles:
// addr(row,k) = ((row>>4)*(K>>3) + (k>>3))*128 + (row&15)*8 + (k&7)
__device__ __forceinline__ long ftaddr(int row, int k, int K) {
  return ((long)(row >> 4) * (K >> 3) + (k >> 3)) * 128 + (row & 15) * 8 + (k & 7);
}

// ---------------- fp32 row-major -> FT split planes ----------------
__global__ void k_cvtft(const float* __restrict__ in, short* __restrict__ oh,
                        short* __restrict__ ol, int ktShift, int n8) {
  int t = blockIdx.x * 256 + threadIdx.x;
  if (t >= n8) return;
  int kt = 1 << ktShift;              // K/8
  int row = t >> ktShift;
  int kc = t & (kt - 1);
  const float* p = in + ((long)row << (ktShift + 3)) + kc * 8;
  float4 v0 = *(const float4*)p;
  float4 v1 = *(const float4*)(p + 4);
  short8 h8, l8;
  bfpair q;
  q = split2p(v0.x); h8[0] = q.hi; l8[0] = q.lo;
  q = split2p(v0.y); h8[1] = q.hi; l8[1] = q.lo;
  q = split2p(v0.z); h8[2] = q.hi; l8[2] = q.lo;
  q = split2p(v0.w); h8[3] = q.hi; l8[3] = q.lo;
  q = split2p(v1.x); h8[4] = q.hi; l8[4] = q.lo;
  q = split2p(v1.y); h8[5] = q.hi; l8[5] = q.lo;
  q = split2p(v1.z); h8[6] = q.hi; l8[6] = q.lo;
  q = split2p(v1.w); h8[7] = q.hi; l8[7] = q.lo;
  long o = ((long)(row >> 4) * kt + kc) * 128 + (row & 15) * 8;
  *(short8*)(oh + o) = h8;
  *(short8*)(ol + o) = l8;
}

// ---------------- hid = relu(ctx @ hfc1_w^T + b), FT planes (rows=32,K=512) --
__global__ __launch_bounds__(512) void k_hid(const float* __restrict__ cvec,
                                             const float* __restrict__ w,
                                             const float* __restrict__ bias,
                                             short* __restrict__ hh,
                                             short* __restrict__ hl) {
  int lb = blockIdx.x;            // l*32 + b
  int b  = lb & 31;
  int j  = threadIdx.x;
  __shared__ float cs[KCTX];
  if (j < KCTX) cs[j] = cvec[b * KCTX + j];
  __syncthreads();
  int l = lb >> 5;
  const float* wr = w + (long)(l * HID_ + j) * KCTX;
  float s = bias[l * HID_ + j];
  #pragma unroll
  for (int c = 0; c < KCTX; c += 4) {
    float4 cv = *(const float4*)(cs + c);
    float4 wv = *(const float4*)(wr + c);
    s += cv.x * wv.x + cv.y * wv.y + cv.z * wv.z + cv.w * wv.w;
  }
  s = fmaxf(s, 0.f);
  bfpair p = split2p(s);
  long o = (long)l * 32 * HID_ + ((long)(b >> 4) * 64 + (j >> 3)) * 128 + (b & 15) * 8 + (j & 7);
  hh[o] = p.hi;
  hl[o] = p.lo;
}

// ---------------- k_flat: flat = hid @ hfc2_w^T + b ----------------
// M=32 (batch), K=512, N=181248. W staged f32->bf16 planes in swizzled LDS.
// Outputs routed by region into FT weight buffers + f32 bias buffers.
__device__ __forceinline__ void store_flat(int b, int trow, float v,
    short* __restrict__ awh, short* __restrict__ awl,
    short* __restrict__ f1h, short* __restrict__ f1l,
    short* __restrict__ f2h, short* __restrict__ f2l,
    float* __restrict__ ab, float* __restrict__ f1b, float* __restrict__ f2b) {
  if (trow < OFF_AB) {
    int e = trow >> 7, d = trow & 127;
    long a = (long)b * 49152 + ftaddr(e, d, 128);
    bfpair p = split2p(v); awh[a] = p.hi; awl[a] = p.lo;
  } else if (trow < OFF_F1W) {
    ab[b * 384 + trow - OFF_AB] = v;
  } else if (trow < OFF_F1B) {
    int i = trow - OFF_F1W; int f = i >> 7, d = i & 127;
    long a = (long)b * 65536 + ftaddr(f, d, 128);
    bfpair p = split2p(v); f1h[a] = p.hi; f1l[a] = p.lo;
  } else if (trow < OFF_F2W) {
    f1b[b * 512 + trow - OFF_F1B] = v;
  } else if (trow < OFF_F2B) {
    int i = trow - OFF_F2W; int dd = i >> 9, f = i & 511;
    long a = (long)b * 65536 + ftaddr(dd, f, 512);
    bfpair p = split2p(v); f2h[a] = p.hi; f2l[a] = p.lo;
  } else {
    f2b[b * 128 + trow - OFF_F2B] = v;
  }
}

__global__ __launch_bounds__(256) void k_flat(
    const short* __restrict__ hidh, const short* __restrict__ hidl,  // FT(32,512)
    const float* __restrict__ W, const float* __restrict__ bias,
    short* __restrict__ awh, short* __restrict__ awl,
    short* __restrict__ f1h, short* __restrict__ f1l,
    short* __restrict__ f2h, short* __restrict__ f2l,
    float* __restrict__ ab, float* __restrict__ f1b, float* __restrict__ f2b) {
  __shared__ short wls[2][64 * 128];   // 32 KB, swizzled
  const int tid = threadIdx.x, wave = tid >> 6, lane = tid & 63;
  const int r = lane & 15, g = lane >> 4;
  const int nb0 = blockIdx.x * 64;
  const short* pAh = hidh + g * 128 + r * 8;
  const short* pAl = hidl + g * 128 + r * 8;
  f32x4 acc0 = {0, 0, 0, 0}, acc1 = {0, 0, 0, 0};
  for (int c0 = 0; c0 < 512; c0 += 128) {
    __syncthreads();
    // stage: 64 W rows x 128 cols f32 -> split planes, swizzled
    #pragma unroll
    for (int rnd = 0; rnd < 8; ++rnd) {
      int row = rnd * 8 + (tid >> 5);
      int col = (tid & 31) * 4;
      float4 wv = *(const float4*)(W + (long)(nb0 + row) * HID_ + c0 + col);
      short4v h4, l4;
      bfpair q;
      q = split2p(wv.x); h4[0] = q.hi; l4[0] = q.lo;
      q = split2p(wv.y); h4[1] = q.hi; l4[1] = q.lo;
      q = split2p(wv.z); h4[2] = q.hi; l4[2] = q.lo;
      q = split2p(wv.w); h4[3] = q.hi; l4[3] = q.lo;
      int sidx = row * 128 + (col ^ ((row & 7) << 3));
      *(short4v*)&wls[0][sidx] = h4;
      *(short4v*)&wls[1][sidx] = l4;
    }
    __syncthreads();
    #pragma unroll
    for (int kk = 0; kk < 4; ++kk) {
      long ao = (long)(c0 * 16) + kk * 512;   // ((c0>>3)+kk*4)*128
      short8 ah0 = *(const short8*)(pAh + ao);
      short8 ah1 = *(const short8*)(pAh + 8192 + ao);
      short8 al0 = *(const short8*)(pAl + ao);
      short8 al1 = *(const short8*)(pAl + 8192 + ao);
      int wrow = wave * 16 + r;
      int widx = wrow * 128 + ((kk * 32 + g * 8) ^ ((r & 7) << 3));
      short8 wh = *(const short8*)&wls[0][widx];
      short8 wl = *(const short8*)&wls[1][widx];
      acc0 = MFMA16(ah0, wl, acc0, 0, 0, 0);
      acc0 = MFMA16(al0, wh, acc0, 0, 0, 0);
      acc0 = MFMA16(ah0, wh, acc0, 0, 0, 0);
      acc1 = MFMA16(ah1, wl, acc1, 0, 0, 0);
      acc1 = MFMA16(al1, wh, acc1, 0, 0, 0);
      acc1 = MFMA16(ah1, wh, acc1, 0, 0, 0);
    }
  }
  int trow = nb0 + wave * 16 + r;
  float bv = bias[trow];
  #pragma unroll
  for (int reg = 0; reg < 4; ++reg) {
    store_flat(g * 4 + reg, trow, acc0[reg] + bv, awh, awl, f1h, f1l, f2h, f2l, ab, f1b, f2b);
    store_flat(g * 4 + reg + 16, trow, acc1[reg] + bv, awh, awl, f1h, f1l, f2h, f2l, ab, f1b, f2b);
  }
}

// ---------------- generic batched split-MFMA GEMM, FT operands ----------------
// out[b][m][n] = act( sum_k A[b][m][k]*W[b][n][k] + bias[n] ), M=512.
// A: FT(512,K) stride sA; W: FT(*,K) stride sW; bias f32 at stride sB (0=shared).
// EPI: 0 = FT split planes out (p0,p1; operand-K = N); 1 = in_proj (+pe, p0=h_f
//      f32 linear, p1/p2 = FT planes, N=128); 2 = f32 linear (p0);
//      3 = vt split planes FT(32,512) per (b,h) (p0,p1).
template <int K, int EPI, bool RELU>
__global__ __launch_bounds__(256) void k_gemm(
    const short* __restrict__ Ah, const short* __restrict__ Al, long sA,
    const short* __restrict__ Wh, const short* __restrict__ Wl, long sW,
    const float* __restrict__ biasP, long sB,
    void* __restrict__ p0, void* __restrict__ p1, void* __restrict__ p2,
    const float* __restrict__ pe, int N) {
  const int tid = threadIdx.x, wave = tid >> 6, lane = tid & 63;
  const int r = lane & 15, g = lane >> 4;
  const int b = blockIdx.z;
  const int m0 = blockIdx.y * 64 + (wave & 1) * 32;
  const int n0 = blockIdx.x * 128 + (wave >> 1) * 64;
  const long KT = (long)K * 16;
  const short* pAh = Ah + (long)b * sA + (m0 >> 4) * KT + g * 128 + r * 8;
  const short* pAl = Al + (long)b * sA + (m0 >> 4) * KT + g * 128 + r * 8;
  const short* pWh = Wh + (long)b * sW + (n0 >> 4) * KT + g * 128 + r * 8;
  const short* pWl = Wl + (long)b * sW + (n0 >> 4) * KT + g * 128 + r * 8;
  f32x4 acc[2][4] = {{{0,0,0,0},{0,0,0,0},{0,0,0,0},{0,0,0,0}},
                     {{0,0,0,0},{0,0,0,0},{0,0,0,0},{0,0,0,0}}};
  for (int kk = 0; kk < K / 32; ++kk) {
    long ko = (long)kk * 512;
    short8 a0h = *(const short8*)(pAh + ko);
    short8 a1h = *(const short8*)(pAh + KT + ko);
    short8 a0l = *(const short8*)(pAl + ko);
    short8 a1l = *(const short8*)(pAl + KT + ko);
    #pragma unroll
    for (int ns = 0; ns < 4; ++ns) {
      short8 wh = *(const short8*)(pWh + ns * KT + ko);
      short8 wl = *(const short8*)(pWl + ns * KT + ko);
      acc[0][ns] = MFMA16(a0h, wl, acc[0][ns], 0, 0, 0);
      acc[0][ns] = MFMA16(a0l, wh, acc[0][ns], 0, 0, 0);
      acc[0][ns] = MFMA16(a0h, wh, acc[0][ns], 0, 0, 0);
      acc[1][ns] = MFMA16(a1h, wl, acc[1][ns], 0, 0, 0);
      acc[1][ns] = MFMA16(a1l, wh, acc[1][ns], 0, 0, 0);
      acc[1][ns] = MFMA16(a1h, wh, acc[1][ns], 0, 0, 0);
    }
  }
  #pragma unroll
  for (int ms = 0; ms < 2; ++ms) {
    #pragma unroll
    for (int ns = 0; ns < 4; ++ns) {
      int ccol = n0 + ns * 16 + r;
      float bv = biasP[(long)b * sB + ccol];
      #pragma unroll
      for (int reg = 0; reg < 4; ++reg) {
        int crow = m0 + ms * 16 + g * 4 + reg;
        float v = acc[ms][ns][reg] + bv;
        if constexpr (RELU) v = fmaxf(v, 0.f);
        if constexpr (EPI == 0) {
          long o = (long)b * 512 * N + (long)(crow >> 4) * (N * 16)
                 + (long)(ccol >> 3) * 128 + (crow & 15) * 8 + (ccol & 7);
          bfpair sp = split2p(v);
          ((short*)p0)[o] = sp.hi;
          ((short*)p1)[o] = sp.lo;
        } else if constexpr (EPI == 1) {
          v += pe[crow * D_ + ccol];
          ((float*)p0)[((long)b * S_ + crow) * D_ + ccol] = v;
          long o = (long)b * 65536 + (long)(crow >> 4) * 2048
                 + (ccol >> 3) * 128 + (crow & 15) * 8 + (ccol & 7);
          bfpair sp = split2p(v);
          ((short*)p1)[o] = sp.hi;
          ((short*)p2)[o] = sp.lo;
        } else if constexpr (EPI == 2) {
          ((float*)p0)[((long)b * S_ + crow) * N + ccol] = v;
        } else {  // EPI == 3: vt FT(32,512) per (b,h)
          int hh2 = ccol >> 5, dd = ccol & 31;
          long o = (long)(b * 4 + hh2) * 16384 + (dd >> 4) * 8192
                 + (crow >> 3) * 128 + (dd & 15) * 8 + (crow & 7);
          bfpair sp = split2p(v);
          ((short*)p0)[o] = sp.hi;
          ((short*)p1)[o] = sp.lo;
        }
      }
    }
  }
}

// ---------------- attention (FT operands) ----------------
__global__ __launch_bounds__(128) void k_attn(const short* __restrict__ qkh,
                                              const short* __restrict__ qkl,
                                              const short* __restrict__ vth,
                                              const short* __restrict__ vtl,
                                              short* __restrict__ ch,
                                              short* __restrict__ cl) {
  __shared__ __align__(16) float scr[2][16][516];
  const int tid = threadIdx.x, wave = tid >> 6, lane = tid & 63;
  const int r = lane & 15, g = lane >> 4;
  const int b = blockIdx.z, hh = blockIdx.y;
  const int m0 = blockIdx.x * 32 + wave * 16;
  const long qb = (long)b * 131072;
  const long qoff = qb + (long)(m0 >> 4) * 4096 + (hh * 4 + g) * 128 + r * 8;
  short8 qh = *(const short8*)(qkh + qoff);
  short8 ql = *(const short8*)(qkl + qoff);
  const float sc = 0.17677669529663687f;  // 1/sqrt(32)
  for (int n0 = 0; n0 < S_; n0 += 16) {
    long koff = qb + (long)(n0 >> 4) * 4096 + (16 + hh * 4 + g) * 128 + r * 8;
    short8 kh = *(const short8*)(qkh + koff);
    short8 kl = *(const short8*)(qkl + koff);
    f32x4 s = {0, 0, 0, 0};
    s = MFMA16(qh, kl, s, 0, 0, 0);
    s = MFMA16(ql, kh, s, 0, 0, 0);
    s = MFMA16(qh, kh, s, 0, 0, 0);
    #pragma unroll
    for (int reg = 0; reg < 4; ++reg)
      scr[wave][g * 4 + reg][n0 + r] = s[reg] * sc;
  }
  __syncthreads();
  for (int row = 0; row < 16; ++row) {
    float v[8];
    #pragma unroll
    for (int i = 0; i < 8; ++i) v[i] = scr[wave][row][lane + i * 64];
    float m = v[0];
    #pragma unroll
    for (int i = 1; i < 8; ++i) m = fmaxf(m, v[i]);
    #pragma unroll
    for (int o = 32; o > 0; o >>= 1) m = fmaxf(m, __shfl_xor(m, o));
    float ssum = 0.f;
    #pragma unroll
    for (int i = 0; i < 8; ++i) { v[i] = __expf(v[i] - m); ssum += v[i]; }
    #pragma unroll
    for (int o = 32; o > 0; o >>= 1) ssum += __shfl_xor(ssum, o);
    float inv = 1.f / ssum;
    #pragma unroll
    for (int i = 0; i < 8; ++i) scr[wave][row][lane + i * 64] = v[i] * inv;
  }
  __syncthreads();
  f32x4 o0 = {0, 0, 0, 0}, o1 = {0, 0, 0, 0};
  const long vb = (long)(b * 4 + hh) * 16384;
  for (int kt = 0; kt < 16; ++kt) {
    float4 pv0 = *(const float4*)&scr[wave][r][kt * 32 + g * 8];
    float4 pv1 = *(const float4*)&scr[wave][r][kt * 32 + g * 8 + 4];
    short8 pah, pal;
    bfpair p;
    p = split2p(pv0.x); pah[0] = p.hi; pal[0] = p.lo;
    p = split2p(pv0.y); pah[1] = p.hi; pal[1] = p.lo;
    p = split2p(pv0.z); pah[2] = p.hi; pal[2] = p.lo;
    p = split2p(pv0.w); pah[3] = p.hi; pal[3] = p.lo;
    p = split2p(pv1.x); pah[4] = p.hi; pal[4] = p.lo;
    p = split2p(pv1.y); pah[5] = p.hi; pal[5] = p.lo;
    p = split2p(pv1.z); pah[6] = p.hi; pal[6] = p.lo;
    p = split2p(pv1.w); pah[7] = p.hi; pal[7] = p.lo;
    long vo = vb + (long)(kt * 4 + g) * 128 + r * 8;
    short8 vh0 = *(const short8*)(vth + vo);
    short8 vh1 = *(const short8*)(vth + vo + 8192);
    short8 vl0 = *(const short8*)(vtl + vo);
    short8 vl1 = *(const short8*)(vtl + vo + 8192);
    o0 = MFMA16(pah, vl0, o0, 0, 0, 0);
    o0 = MFMA16(pal, vh0, o0, 0, 0, 0);
    o0 = MFMA16(pah, vh0, o0, 0, 0, 0);
    o1 = MFMA16(pah, vl1, o1, 0, 0, 0);
    o1 = MFMA16(pal, vh1, o1, 0, 0, 0);
    o1 = MFMA16(pah, vh1, o1, 0, 0, 0);
  }
  #pragma unroll
  for (int reg = 0; reg < 4; ++reg) {
    int srow = m0 + g * 4 + reg;
    int col0 = hh * 32 + r;
    long o = (long)b * 65536 + (long)(srow >> 4) * 2048
           + (col0 >> 3) * 128 + (srow & 15) * 8 + (col0 & 7);
    bfpair sp0 = split2p(o0[reg]);
    ch[o] = sp0.hi; cl[o] = sp0.lo;
    long o2 = o + 2 * 128;   // col0+16 -> (col>>3)+2
    bfpair sp1 = split2p(o1[reg]);
    ch[o2] = sp1.hi; cl[o2] = sp1.lo;
  }
}

// ---------------- layernorm: h = LN(h + alpha*y)*g + b -> f32 + FT planes ----
__global__ __launch_bounds__(256) void k_ln(const float* hin, const float* __restrict__ y,
                                            const float* __restrict__ g,
                                            const float* __restrict__ bta,
                                            const float* __restrict__ alpha,
                                            float* hout, short* __restrict__ hh,
                                            short* __restrict__ hl) {
  long row = (long)blockIdx.x * 4 + (threadIdx.x >> 6);
  int lane = threadIdx.x & 63;
  float a = alpha[0];
  long base = row * D_;
  int c = lane * 2;
  float2 hv = *(const float2*)(hin + base + c);
  float2 yv = *(const float2*)(y + base + c);
  float t0 = hv.x + a * yv.x, t1 = hv.y + a * yv.y;
  float s = t0 + t1;
  #pragma unroll
  for (int o = 32; o > 0; o >>= 1) s += __shfl_xor(s, o);
  float mu = s * (1.f / 128.f);
  float d0 = t0 - mu, d1 = t1 - mu;
  float q = d0 * d0 + d1 * d1;
  #pragma unroll
  for (int o = 32; o > 0; o >>= 1) q += __shfl_xor(q, o);
  float inv = rsqrtf(q * (1.f / 128.f) + 1e-5f);
  float o0 = d0 * inv * g[c] + bta[c];
  float o1 = d1 * inv * g[c + 1] + bta[c + 1];
  float2 ov = {o0, o1};
  *(float2*)(hout + base + c) = ov;
  long o = (long)(row >> 4) * 2048 + (c >> 3) * 128 + (row & 15) * 8 + (c & 7);
  short2v hv2, lv2;
  bfpair p0 = split2p(o0);
  bfpair p1 = split2p(o1);
  hv2[0] = p0.hi; lv2[0] = p0.lo;
  hv2[1] = p1.hi; lv2[1] = p1.lo;
  *(short2v*)(hh + o) = hv2;
  *(short2v*)(hl + o) = lv2;
}

// ---------------- head ----------------
__global__ __launch_bounds__(64) void k_head(const float* __restrict__ h,
                                             const float* __restrict__ hw,
                                             const float* __restrict__ hb,
                                             float* __restrict__ out) {
  int b = blockIdx.x, lane = threadIdx.x;
  const float* hr = h + ((long)b * S_ + (S_ - 1)) * D_;
  float v = hr[lane] * hw[lane] + hr[lane + 64] * hw[lane + 64];
  #pragma unroll
  for (int o = 32; o > 0; o >>= 1) v += __shfl_xor(v, o);
  if (lane == 0) out[b] = v + hb[0];
}

// ---------------- host ----------------
extern "C" void kernel_launch(void* const* d_in, const int* in_sizes, int n_in,
                              void* d_out, int out_size, void* d_ws, size_t ws_size,
                              hipStream_t stream) {
  const float* x    = (const float*)d_in[0];
  const float* cvec = (const float*)d_in[1];
  const float* ipw  = (const float*)d_in[2];
  const float* ipb  = (const float*)d_in[3];
  const float* pe   = (const float*)d_in[4];
  const float* h1w  = (const float*)d_in[5];
  const float* h1b  = (const float*)d_in[6];
  const float* h2w  = (const float*)d_in[7];
  const float* h2b  = (const float*)d_in[8];
  const float* opw  = (const float*)d_in[9];
  const float* opb  = (const float*)d_in[10];
  const float* ln1g = (const float*)d_in[11];
  const float* ln1b = (const float*)d_in[12];
  const float* ln2g = (const float*)d_in[13];
  const float* ln2b = (const float*)d_in[14];
  const float* a1   = (const float*)d_in[15];
  const float* a2   = (const float*)d_in[16];
  const float* hw   = (const float*)d_in[17];
  const float* hb   = (const float*)d_in[18];
  float* out = (float*)d_out;

  char* ws = (char*)d_ws;
  size_t off = 0;
  auto alloc = [&](size_t n) { void* p = ws + off; off = (off + n + 255) & ~(size_t)255; return p; };

  short* ff1h  = (short*)alloc((size_t)B_ * S_ * 512 * 2);   // 16.8 MB, aliases xFh
  short* ff1l  = (short*)alloc((size_t)B_ * S_ * 512 * 2);
  short* xFh   = ff1h;    // x planes dead before ff1 written
  short* xFl   = ff1l;
  float* h_f   = (float*)alloc((size_t)B_ * S_ * D_ * 4);
  short* hFh   = (short*)alloc((size_t)B_ * S_ * D_ * 2);
  short* hFl   = (short*)alloc((size_t)B_ * S_ * D_ * 2);
  short* hidFh = (short*)alloc((size_t)L_ * 32 * HID_ * 2);
  short* hidFl = (short*)alloc((size_t)L_ * 32 * HID_ * 2);
  short* awFh  = (short*)alloc((size_t)B_ * 49152 * 2);
  short* awFl  = (short*)alloc((size_t)B_ * 49152 * 2);
  short* f1wFh = (short*)alloc((size_t)B_ * 65536 * 2);
  short* f1wFl = (short*)alloc((size_t)B_ * 65536 * 2);
  short* f2wFh = (short*)alloc((size_t)B_ * 65536 * 2);
  short* f2wFl = (short*)alloc((size_t)B_ * 65536 * 2);
  float* abF   = (float*)alloc((size_t)B_ * 384 * 4);
  float* f1bF  = (float*)alloc((size_t)B_ * 512 * 4);
  float* f2bF  = (float*)alloc((size_t)B_ * 128 * 4);
  short* qkFh  = (short*)alloc((size_t)B_ * S_ * 256 * 2);   // aliased as yb
  short* qkFl  = (short*)alloc((size_t)B_ * S_ * 256 * 2);
  float* yb    = (float*)qkFh;                               // qk dead after attn
  short* vtFh  = (short*)alloc((size_t)B_ * H_ * 32 * S_ * 2);
  short* vtFl  = (short*)alloc((size_t)B_ * H_ * 32 * S_ * 2);
  short* cxFh  = (short*)alloc((size_t)B_ * S_ * D_ * 2);
  short* cxFl  = (short*)alloc((size_t)B_ * S_ * D_ * 2);
  short* ipwFh = (short*)alloc((size_t)D_ * INDIM * 2);
  short* ipwFl = (short*)alloc((size_t)D_ * INDIM * 2);
  short* opwFh = (short*)alloc((size_t)L_ * D_ * D_ * 2);
  short* opwFl = (short*)alloc((size_t)L_ * D_ * D_ * 2);

  // conversions to FT split planes
  k_cvtft<<<(B_ * S_ * INDIM / 8 + 255) / 256, 256, 0, stream>>>(x, xFh, xFl, 5, B_ * S_ * INDIM / 8);
  k_cvtft<<<16, 256, 0, stream>>>(ipw, ipwFh, ipwFl, 5, D_ * INDIM / 8);
  k_cvtft<<<16, 256, 0, stream>>>(opw, opwFh, opwFl, 4, L_ * D_ * D_ / 8);

  k_hid<<<L_ * 32, 512, 0, stream>>>(cvec, h1w, h1b, hidFh, hidFl);

  // h = x @ in_proj^T + b + pe
  k_gemm<INDIM, 1, false><<<dim3(1, 8, B_), 256, 0, stream>>>(
      xFh, xFl, (long)S_ * INDIM, ipwFh, ipwFl, 0, ipb, 0,
      h_f, hFh, hFl, pe, 128);

  for (int l = 0; l < L_; ++l) {
    k_flat<<<TOTAL_ / 64, 256, 0, stream>>>(
        hidFh + (long)l * 32 * HID_, hidFl + (long)l * 32 * HID_,
        h2w + (long)l * TOTAL_ * HID_, h2b + (long)l * TOTAL_,
        awFh, awFl, f1wFh, f1wFl, f2wFh, f2wFl, abF, f1bF, f2bF);
    // q|k  (flat rows 0..255)
    k_gemm<D_, 0, false><<<dim3(2, 8, B_), 256, 0, stream>>>(
        hFh, hFl, (long)S_ * D_, awFh, awFl, 49152, abF, 384,
        qkFh, qkFl, nullptr, nullptr, 256);
    // v -> vt (flat rows 256..383; FT row offset 256 = linear 256*128)
    k_gemm<D_, 3, false><<<dim3(1, 8, B_), 256, 0, stream>>>(
        hFh, hFl, (long)S_ * D_, awFh + 32768, awFl + 32768, 49152, abF + 256, 384,
        vtFh, vtFl, nullptr, nullptr, 128);
    k_attn<<<dim3(S_ / 32, H_, B_), 128, 0, stream>>>(qkFh, qkFl, vtFh, vtFl, cxFh, cxFl);
    // out_proj -> yb (f32 linear)
    k_gemm<D_, 2, false><<<dim3(1, 8, B_), 256, 0, stream>>>(
        cxFh, cxFl, (long)S_ * D_, opwFh + l * 16384, opwFl + l * 16384, 0,
        opb + l * D_, 0, yb, nullptr, nullptr, nullptr, 128);
    k_ln<<<B_ * S_ / 4, 256, 0, stream>>>(h_f, yb, ln1g + l * D_, ln1b + l * D_,
                                          a1 + l, h_f, hFh, hFl);
    // ffn1 (relu) -> ff1 FT(512,512)
    k_gemm<D_, 0, true><<<dim3(4, 8, B_), 256, 0, stream>>>(
        hFh, hFl, (long)S_ * D_, f1wFh, f1wFl, 65536, f1bF, 512,
        ff1h, ff1l, nullptr, nullptr, 512);
    // ffn2 -> yb (f32 linear)
    k_gemm<512, 2, false><<<dim3(1, 8, B_), 256, 0, stream>>>(
        ff1h, ff1l, (long)S_ * 512, f2wFh, f2wFl, 65536, f2bF, 128,
        yb, nullptr, nullptr, nullptr, 128);
    k_ln<<<B_ * S_ / 4, 256, 0, stream>>>(h_f, yb, ln2g + l * D_, ln2b + l * D_,
                                          a2 + l, h_f, hFh, hFl);
  }
  k_head<<<B_, 64, 0, stream>>>(h_f, hw, hb, out);
}